// Round 1
// 342.219 us; speedup vs baseline: 1.0255x; 1.0255x over previous
//
#include <hip/hip_runtime.h>
#include <math.h>

#define B_    4
#define T_    8192
#define C_    1024
#define E_    64
#define NTOK  (B_*T_)          // 32768
#define KSEL  2

// d_out offsets (in floats): idx, scores, probs, importance, load
#define OFF_IDX    0
#define OFF_SCORES (NTOK*KSEL)               // 65536
#define OFF_PROBS  (2*NTOK*KSEL)             // 131072
#define OFF_IMP    (OFF_PROBS + NTOK*E_)     // 2228224
#define OFF_LOAD   (OFF_IMP + E_)            // 2228288

// workspace offsets (bytes)
#define WS_W32    0                          // 1024*64*4 = 256 KB ([d][e], refine)
#define WS_BSWH   262144                     // 128 KB bf16 hi, MFMA-frag order
#define WS_BSWL   393216                     // 128 KB bf16 lo
#define WS_LB64   524288                     // 4*64*8 = 2 KB  (zeroed w/ CNT)
#define WS_CNT    526336                     // 4
#define WS_LIST   526400                     // REFINE_CAP*4 = 32 KB

#define REFINE_CAP 8192
#define REFINE_EPS 3e-4f

typedef __attribute__((ext_vector_type(8))) short short8;
typedef __attribute__((ext_vector_type(4))) float f32x4;

// ---------------------------------------------------------------------------
// K_prep: 512 blocks, block bid owns 4 d's (d0=bid*4, d in 0..2047), full C
// in fp64 with even/odd-c split accumulator chains (halves the dependent
// v_fma_f64 chain; fp64 reassociation is ~1e-13, far below REFINE_EPS).
// 2 blocks/CU (vs 1 before) doubles latency hiding.
// d<1024: wcomb32[d][e] + bf16 hi/lo split -> bsw slabs (MFMA-frag order)
// d>=1024: partial lbias[b][e] contributions via fp64 atomics (pre-reduced).
// Block 0 also zeroes importance/load region of out.
// ---------------------------------------------------------------------------
__global__ __launch_bounds__(256) void k_prep(const float* __restrict__ Wg,
                                              const float* __restrict__ Wc,
                                              const float* __restrict__ cond,
                                              float* __restrict__ wcomb32,
                                              short* __restrict__ bswH,
                                              short* __restrict__ bswL,
                                              double* __restrict__ lbias64,
                                              float* __restrict__ out) {
    __shared__ float wg_s[64 * 64];   // [c][e]  (transposed at stage)
    __shared__ float wc_s[64 * 4];    // [c][d_local]
    __shared__ double red[256];

    const int tid = threadIdx.x;
    const int e   = tid & 63;
    const int dg  = tid >> 6;                  // 0..3
    const int d0  = blockIdx.x * 4;

    if (blockIdx.x == 0 && tid < 2 * E_) out[OFF_IMP + tid] = 0.f;

    double ae = 0.0, ao = 0.0;                 // even / odd c chains

    for (int c0 = 0; c0 < C_; c0 += 64) {
        __syncthreads();
        // stage Wg chunk transposed: wg_s[c][e]
#pragma unroll
        for (int k = 0; k < 4; ++k) {
            int li = tid + k * 256;
            int r = li >> 4, c4 = (li & 15) * 4;
            float4 v = *(const float4*)&Wg[(size_t)r * 1024 + c0 + c4];
            wg_s[(c4 + 0) * 64 + r] = v.x;
            wg_s[(c4 + 1) * 64 + r] = v.y;
            wg_s[(c4 + 2) * 64 + r] = v.z;
            wg_s[(c4 + 3) * 64 + r] = v.w;
        }
        // stage Wc column slab: wc_s[c][dl], 256 floats (tid<128, float2 each)
        if (tid < 128) {
            int cc = tid >> 1, dd0 = (tid & 1) * 2;
            *(float2*)&wc_s[cc * 4 + dd0] =
                *(const float2*)&Wc[(size_t)(c0 + cc) * 2048 + d0 + dd0];
        }
        __syncthreads();
#pragma unroll 8
        for (int c = 0; c < 64; c += 2) {
            ae += (double)wg_s[(c + 0) * 64 + e] * (double)wc_s[(c + 0) * 4 + dg];
            ao += (double)wg_s[(c + 1) * 64 + e] * (double)wc_s[(c + 1) * 4 + dg];
        }
    }
    const double acc = ae + ao;

    if (d0 < 1024) {
        const int d = d0 + dg;
        const int et = e >> 4, nn = e & 15;
        float f = (float)acc;
        wcomb32[d * 64 + e] = f;
        unsigned u = __float_as_uint(f);
        short hi = (short)(u >> 16);
        float r = f - __uint_as_float(u & 0xFFFF0000u);
        short lo = (short)(__float_as_uint(r) >> 16);
        int kchunk = d >> 5, qsel = (d >> 3) & 3, j = d & 7;
        int idx = ((kchunk * 4 + et) * 64 + qsel * 16 + nn) * 8 + j;
        bswH[idx] = hi;
        bswL[idx] = lo;
    } else {
        const int da = d0 - 1024 + dg;
#pragma unroll
        for (int b = 0; b < 4; ++b) {
            double pb = (double)cond[b * 1024 + da] * acc;
            __syncthreads();
            red[tid] = pb;
            __syncthreads();
            if (tid < 64) {
                double s = red[tid] + red[tid + 64] + red[tid + 128] + red[tid + 192];
#if __has_builtin(__builtin_amdgcn_global_atomic_fadd_f64)
                unsafeAtomicAdd(&lbias64[b * 64 + tid], s);
#else
                atomicAdd(&lbias64[b * 64 + tid], s);
#endif
            }
        }
    }
}

// ---------------------------------------------------------------------------
// split 8 consecutive fp32 (from LDS-read registers) into bf16 hi + lo
// ---------------------------------------------------------------------------
__device__ __forceinline__ void split8(const float* xv, short8& h, short8& l) {
#pragma unroll
    for (int j = 0; j < 8; ++j) {
        unsigned u = __float_as_uint(xv[j]);
        h[j] = (short)(u >> 16);
        float r = xv[j] - __uint_as_float(u & 0xFFFF0000u);
        l[j] = (short)(__float_as_uint(r) >> 16);
    }
}

// ---------------------------------------------------------------------------
// K_main: logits = x @ Wcomb + lbias[b], bf16-split MFMA.
// 1024 blocks x 256 thr (4 blocks/CU, 16 waves/CU = 2x old occupancy).
// Block = 32 tokens; wave (th,eh) = token-half x expert-half:
//   16 tokens x 32 experts, full K, 2 accumulators.
// DOUBLE-BUFFERED reg-staging: issue next tile's global loads into regs
// BEFORE the MFMA phase, ds_write after compute, ONE barrier per tile —
// load latency hides under compute. Plain (cacheable) loads so x stays
// LLC-resident across iterations (128 MB < 256 MB L3).
// A/B frag: [m|n=lane&15][k=(lane>>4)*8+j]; C/D: col=lane&15, row=(lane>>4)*4+r.
// ---------------------------------------------------------------------------
#define MT    32
#define XSTR  132         // LDS x-tile row stride in floats (bank spread)
#define BUFSZ (MT * XSTR) // 4224 floats per buffer
#define ROWP  65          // epilogue logits row stride

__global__ __launch_bounds__(256, 4) void k_main(const float* __restrict__ x,
                                                 const short* __restrict__ bswH,
                                                 const short* __restrict__ bswL,
                                                 const double* __restrict__ lbias64,
                                                 float* __restrict__ out,
                                                 unsigned int* __restrict__ ref_cnt,
                                                 int* __restrict__ ref_list) {
    __shared__ float xs[2 * BUFSZ];   // 33.8 KB double-buffered x-tile; reused for logits
    __shared__ float invs[MT];
    __shared__ unsigned int cnts[E_];

    const int tid    = threadIdx.x;
    const int wid    = tid >> 6;
    const int lane   = tid & 63;
    const int nn     = lane & 15;
    const int qsel   = lane >> 4;
    const int th     = wid & 1;               // token half (0..1)
    const int eh     = wid >> 1;              // expert half (0..1)
    const int et0    = eh * 2;
    const int token0 = blockIdx.x * MT;
    const int b      = token0 >> 13;          // /8192

    if (tid < E_) cnts[tid] = 0;

    f32x4 acc[2];
#pragma unroll
    for (int ei = 0; ei < 2; ++ei) acc[ei] = (f32x4){0.f, 0.f, 0.f, 0.f};

    const int srow = tid >> 5;        // 0..7 staging row
    const int scol = (tid & 31) * 4;  // staging float4 column

    f32x4 rg[4];
    // ---- prologue: tile 0 ----
#pragma unroll
    for (int p = 0; p < 4; ++p)
        rg[p] = *(const f32x4*)&x[(size_t)(token0 + p * 8 + srow) * 1024 + scol];
#pragma unroll
    for (int p = 0; p < 4; ++p)
        *(f32x4*)&xs[(p * 8 + srow) * XSTR + scol] = rg[p];
    __syncthreads();

    const float* arow0 = &xs[(th * 16 + nn) * XSTR + qsel * 8];

    for (int t = 0; t < 8; ++t) {     // K-tiles of 128
        const int cur = t & 1;
        // ---- issue next tile's loads (overlap with compute below) ----
        if (t < 7) {
            const int k0 = (t + 1) * 128;
#pragma unroll
            for (int p = 0; p < 4; ++p)
                rg[p] = *(const f32x4*)&x[(size_t)(token0 + p * 8 + srow) * 1024 + k0 + scol];
        }
        // ---- compute current tile ----
        const float* arow = arow0 + cur * BUFSZ;
#pragma unroll
        for (int kc = 0; kc < 4; ++kc) {
            float xv[8];
            *(f32x4*)&xv[0] = *(const f32x4*)(arow + kc * 32);
            *(f32x4*)&xv[4] = *(const f32x4*)(arow + kc * 32 + 4);
            short8 ah, al;
            split8(xv, ah, al);
            const int kchunk = t * 4 + kc;
            const short* bh = bswH + (size_t)(kchunk * 4 + et0) * 512 + lane * 8;
            const short* bl = bswL + (size_t)(kchunk * 4 + et0) * 512 + lane * 8;
#pragma unroll
            for (int ei = 0; ei < 2; ++ei) {
                short8 b_h = *(const short8*)(bh + ei * 512);
                short8 b_l = *(const short8*)(bl + ei * 512);
                acc[ei] = __builtin_amdgcn_mfma_f32_16x16x32_bf16(ah, b_h, acc[ei], 0, 0, 0);
                acc[ei] = __builtin_amdgcn_mfma_f32_16x16x32_bf16(ah, b_l, acc[ei], 0, 0, 0);
                acc[ei] = __builtin_amdgcn_mfma_f32_16x16x32_bf16(al, b_h, acc[ei], 0, 0, 0);
            }
        }
        // ---- write prefetched tile into other buffer, one barrier/tile ----
        if (t < 7) {
#pragma unroll
            for (int p = 0; p < 4; ++p)
                *(f32x4*)&xs[(cur ^ 1) * BUFSZ + (p * 8 + srow) * XSTR + scol] = rg[p];
        }
        __syncthreads();
    }

    // ---- epilogue: logits into reused xs tile [tok][e] (stride ROWP) ----
    const int q4 = qsel * 4;
#pragma unroll
    for (int ei = 0; ei < 2; ++ei) {
        const int et = et0 + ei;
        float lb = (float)lbias64[b * 64 + et * 16 + nn];
#pragma unroll
        for (int r = 0; r < 4; ++r) {
            int tok = th * 16 + q4 + r;
            xs[tok * ROWP + et * 16 + nn] = acc[ei][r] + lb;
        }
    }
    __syncthreads();

    if (tid < MT) {
        const int tk = tid;
        const int base = tk * ROWP;
        float v1 = -1e30f, v2 = -1e30f, v3 = -1e30f;
        int i1 = 0, i2 = 0;
        for (int e = 0; e < E_; ++e) {
            float l = xs[base + e];
            if (l > v1)      { v3 = v2; v2 = v1; i2 = i1; v1 = l; i1 = e; }
            else if (l > v2) { v3 = v2; v2 = l; i2 = e; }
            else if (l > v3) { v3 = l; }
        }
        float sum = 0.f;
        for (int e = 0; e < E_; ++e) {
            float ex = __expf(xs[base + e] - v1);
            xs[base + e] = ex;
            sum += ex;
        }
        invs[tk] = 1.0f / sum;

        const int gt = token0 + tk;
        float s1 = 1.0f / (1.0f + __expf(v2 - v1));   // softmax over top-2
        *(float2*)&out[OFF_IDX + (size_t)gt * 2]    = make_float2((float)i1, (float)i2);
        *(float2*)&out[OFF_SCORES + (size_t)gt * 2] = make_float2(s1, 1.0f - s1);
        atomicAdd(&cnts[i1], 1u);
        atomicAdd(&cnts[i2], 1u);

        float g12 = v1 - v2, g23 = v2 - v3;
        float g = g12 < g23 ? g12 : g23;
        if (g < REFINE_EPS) {
            unsigned int pos = atomicAdd(ref_cnt, 1u);
            if (pos < REFINE_CAP) ref_list[pos] = gt;
        }
    }
    __syncthreads();

    // probs: 2048 floats = 512 float4, coalesced (2 per thread)
    float* probs = out + OFF_PROBS + (size_t)token0 * E_;
#pragma unroll
    for (int k = 0; k < 2; ++k) {
        int li4 = tid + k * 256;
        int tok = li4 >> 4;
        int c4 = (li4 & 15) << 2;
        float inv = invs[tok];
        int o = tok * ROWP + c4;
        *(float4*)&probs[(size_t)li4 * 4] =
            make_float4(xs[o] * inv, xs[o + 1] * inv,
                        xs[o + 2] * inv, xs[o + 3] * inv);
    }

    // importance + load: one atomic each per e per block
    if (tid < E_) {
        const int e = tid;
        float s = 0.f;
        for (int tt = 0; tt < MT; ++tt) s += xs[tt * ROWP + e] * invs[tt];
        atomicAdd(&out[OFF_IMP + e],  s * (1.0f / (float)NTOK));
        atomicAdd(&out[OFF_LOAD + e], (float)cnts[e] * (1.0f / (float)(NTOK * KSEL)));
    }
}

// ---------------------------------------------------------------------------
// K_ref: fp64 re-evaluation of ambiguous tokens. One wave per flagged token,
// lane = expert, 4 split accumulators. Grid 256 (2x waves vs before).
// ---------------------------------------------------------------------------
__global__ __launch_bounds__(256) void k_refine(const float* __restrict__ x,
                                                const float* __restrict__ wcomb32,
                                                const double* __restrict__ lbias64,
                                                const unsigned int* __restrict__ ref_cnt,
                                                const int* __restrict__ ref_list,
                                                float* __restrict__ out) {
    int wave = (int)((blockIdx.x * blockDim.x + threadIdx.x) >> 6);
    int lane = threadIdx.x & 63;
    unsigned int n = *ref_cnt;
    if (n > REFINE_CAP) n = REFINE_CAP;
    const int nwaves = (int)((gridDim.x * blockDim.x) >> 6);

    for (unsigned int wi = wave; wi < n; wi += nwaves) {
        const int gt = ref_list[wi];
        const int b = gt / T_;
        const float* xrow = x + (size_t)gt * C_;
        double a0 = 0.0, a1 = 0.0, a2 = 0.0, a3 = 0.0;
        for (int d = 0; d < C_; d += 4) {
            a0 += (double)xrow[d + 0] * (double)wcomb32[(d + 0) * 64 + lane];
            a1 += (double)xrow[d + 1] * (double)wcomb32[(d + 1) * 64 + lane];
            a2 += (double)xrow[d + 2] * (double)wcomb32[(d + 2) * 64 + lane];
            a3 += (double)xrow[d + 3] * (double)wcomb32[(d + 3) * 64 + lane];
        }
        double acc = ((a0 + a1) + (a2 + a3)) + lbias64[b * 64 + lane];

        double v = acc; int id = lane;
        for (int off = 32; off > 0; off >>= 1) {
            double ov = __shfl_xor(v, off, 64);
            int oid   = __shfl_xor(id, off, 64);
            if (ov > v || (ov == v && oid < id)) { v = ov; id = oid; }
        }
        double v1 = v; int i1 = id;
        v = (lane == i1) ? -1e300 : acc; id = lane;
        for (int off = 32; off > 0; off >>= 1) {
            double ov = __shfl_xor(v, off, 64);
            int oid   = __shfl_xor(id, off, 64);
            if (ov > v || (ov == v && oid < id)) { v = ov; id = oid; }
        }
        double v2 = v; int i2 = id;

        if (lane == 0) {
            float s1 = (float)(1.0 / (1.0 + exp(v2 - v1)));
            *(float2*)&out[OFF_IDX + (size_t)gt * 2]    = make_float2((float)i1, (float)i2);
            *(float2*)&out[OFF_SCORES + (size_t)gt * 2] = make_float2(s1, 1.0f - s1);
        }
    }
}

// ---------------------------------------------------------------------------
extern "C" void kernel_launch(void* const* d_in, const int* in_sizes, int n_in,
                              void* d_out, int out_size, void* d_ws, size_t ws_size,
                              hipStream_t stream) {
    const float* x    = (const float*)d_in[0];   // (4,8192,1024)
    const float* cond = (const float*)d_in[1];   // (4,1024)
    const float* Wg   = (const float*)d_in[2];   // (64,1024)
    const float* Wc   = (const float*)d_in[3];   // (1024,2048)
    float* out = (float*)d_out;
    char*  ws  = (char*)d_ws;

    float*  wcomb32 = (float*)(ws + WS_W32);
    short*  bswH    = (short*)(ws + WS_BSWH);
    short*  bswL    = (short*)(ws + WS_BSWL);
    double* lbias64 = (double*)(ws + WS_LB64);
    unsigned int* ref_cnt = (unsigned int*)(ws + WS_CNT);
    int*    ref_list = (int*)(ws + WS_LIST);

    // zero lbias64 (2 KB) + ref_cnt (adjacent) in one memset
    hipMemsetAsync(ws + WS_LB64, 0, (WS_CNT - WS_LB64) + 64, stream);

    k_prep<<<512, 256, 0, stream>>>(Wg, Wc, cond, wcomb32, bswH, bswL, lbias64, out);
    k_main<<<NTOK / MT, 256, 0, stream>>>(x, bswH, bswL, lbias64, out, ref_cnt, ref_list);
    k_refine<<<256, 256, 0, stream>>>(x, wcomb32, lbias64, ref_cnt, ref_list, out);
}